// Round 5
// baseline (523.400 us; speedup 1.0000x reference)
//
#include <hip/hip_runtime.h>
#include <math.h>

#define NODES_TOTAL 160000
#define NODES_REAL  5000
#define D 128
#define NEG 0.2f
#define KP 136                // padded k-pitch (ushorts)
#define HL (128 * KP)         // ushorts per hi (or lo) plane = 17408
#define WT_L (2 * HL)         // ushorts per layer (hi + lo)  = 34816

typedef unsigned short ushort_t;
typedef unsigned int uint_t;
typedef _Float16 f16;
typedef __attribute__((ext_vector_type(8))) _Float16 f16x8;
typedef __attribute__((ext_vector_type(4))) float f32x4;
union H8 { f16x8 v; f16 h[8]; ushort_t u[8]; };
union HU { f16 h; ushort_t u; };

// f16 split: hi = rn_f16(x), lo = rn_f16(x - hi); hi*B + lo*B residual ~2^-22 rel
__device__ __forceinline__ void split2h(float x, f16& hi, f16& lo) {
    hi = (f16)x;
    lo = (f16)(x - (float)hi);
}
__device__ __forceinline__ uint_t encmax(float f) {
    uint_t b = __float_as_uint(f);
    return b ^ ((uint_t)((int)b >> 31) | 0x80000000u);
}
__device__ __forceinline__ float decmax(uint_t u) {
    uint_t b = (u & 0x80000000u) ? (u ^ 0x80000000u) : ~u;
    return __uint_as_float(b);
}

// ---------------- CSR build ----------------------------------------------------
__global__ void zero_kernel(int* counts, uint_t* gmaxu) {
    int i = blockIdx.x * blockDim.x + threadIdx.x;
    if (i < NODES_REAL) counts[i] = 0;
    if (i < 3) gmaxu[i] = 0u;
}

__global__ void rank_kernel(const int* __restrict__ ei, int* __restrict__ counts,
                            ushort_t* __restrict__ rank16, int Eh) {
    int e = blockIdx.x * blockDim.x + threadIdx.x;
    if (e < Eh) {
        int d = ei[Eh + e];
        int r = atomicAdd(&counts[d], 1);
        rank16[e] = (ushort_t)r;
    }
}

__global__ void scan_kernel(const int* __restrict__ counts, int* __restrict__ offs) {
    __shared__ int sd[1024];
    int t = threadIdx.x;
    int pre[5]; int sum = 0;
    #pragma unroll
    for (int u = 0; u < 5; ++u) {
        int idx = t * 5 + u;
        int c = (idx < NODES_REAL) ? counts[idx] : 0;
        pre[u] = sum; sum += c;
    }
    sd[t] = sum;
    __syncthreads();
    int run = sum;
    for (int o = 1; o < 1024; o <<= 1) {
        int v = (t >= o) ? sd[t - o] : 0;
        __syncthreads();
        sd[t] += v;
        __syncthreads();
    }
    int excl = sd[t] - run;
    #pragma unroll
    for (int u = 0; u < 5; ++u) {
        int idx = t * 5 + u;
        if (idx < NODES_REAL) offs[idx] = excl + pre[u];
    }
    if (t == 1023) offs[NODES_REAL] = excl + run;
}

__global__ void scatter_det(const int* __restrict__ ei, const int* __restrict__ offs,
                            const ushort_t* __restrict__ rank16, ushort_t* __restrict__ esrc,
                            int Eh) {
    int e = blockIdx.x * blockDim.x + threadIdx.x;
    if (e < Eh) {
        int s = ei[e];
        int d = ei[Eh + e];
        esrc[offs[d] + (int)rank16[e]] = (ushort_t)s;
    }
}

// ---------------- W split+transpose into padded f16 layout [n][KP] hi|lo -------
__global__ void wsplit_kernel(const float* __restrict__ Ws, ushort_t* __restrict__ Wt) {
    int l  = blockIdx.x >> 3;
    int n  = (blockIdx.x & 7) * 16 + (threadIdx.x >> 4);
    int k0 = (threadIdx.x & 15) * 8;
    const float* src = Ws + (size_t)l * D * D;
    union { ushort_t u[8]; uint4 v; } hi, lo;
    #pragma unroll
    for (int j = 0; j < 8; ++j) {
        HU h, lw;
        split2h(src[(size_t)(k0 + j) * D + n], h.h, lw.h);
        hi.u[j] = h.u; lo.u[j] = lw.u;
    }
    ushort_t* dhi = Wt + (size_t)l * WT_L + n * KP + k0;
    *(uint4*)dhi = hi.v;
    *(uint4*)(dhi + HL) = lo.v;
}

// ---------------- fused 3-layer MLP for rows [5000,160000) ---------------------
// 512 thr = 8 waves: 4 rowgroups x 2 colgroups; wave tile = 32 rows x 64 cols.
// LDS: W f16 hi/lo (69.6KB) + fp32 scr for the C->A inter-layer handoff (67.6KB)
// = 137KB -> 1 block/CU but 8 waves = 2 waves/SIMD (latency hiding).
__global__ __launch_bounds__(512, 2)
void mlp3_kernel(const float* __restrict__ x, const ushort_t* __restrict__ Wt,
                 const float* __restrict__ bs, float* __restrict__ out) {
    __shared__ ushort_t Wl[WT_L];          // 69632 B
    __shared__ float scr[4][2][16][132];   // 67584 B
    int tid = threadIdx.x;
    int wv = tid >> 6, lane = tid & 63;
    int rg = wv >> 1, cg = wv & 1;
    int q = lane >> 4, m16 = lane & 15;
    int brow0 = NODES_REAL + blockIdx.x * 128;
    int row0 = brow0 + rg * 32;
    int cbase = cg * 64;

    // prefetch layer-0 A tiles (hide HBM latency under first W staging)
    float4 xa[2][4][2];
    #pragma unroll
    for (int rt = 0; rt < 2; ++rt) {
        int r = row0 + rt * 16 + m16;
        if (r > NODES_TOTAL - 1) r = NODES_TOTAL - 1;
        #pragma unroll
        for (int kc = 0; kc < 4; ++kc) {
            const float* gp = x + (size_t)r * D + kc * 32 + q * 8;
            xa[rt][kc][0] = *(const float4*)gp;
            xa[rt][kc][1] = *(const float4*)(gp + 4);
        }
    }

    f32x4 acc[2][4];
    #pragma unroll
    for (int l = 0; l < 3; ++l) {
        __syncthreads();   // prior layer's Wl/scr writes+reads settled
        {
            const uint4* gw = (const uint4*)(Wt + (size_t)l * WT_L);
            uint4* lw = (uint4*)Wl;
            #pragma unroll
            for (int r = 0; r < 9; ++r) {
                int idx = r * 512 + tid;
                if (idx < WT_L / 8) lw[idx] = gw[idx];
            }
        }
        __syncthreads();

        #pragma unroll
        for (int rt = 0; rt < 2; ++rt)
            #pragma unroll
            for (int ct = 0; ct < 4; ++ct) acc[rt][ct] = (f32x4){0.f, 0.f, 0.f, 0.f};

        #pragma unroll
        for (int kc = 0; kc < 4; ++kc) {
            H8 ahi[2], alo[2];
            #pragma unroll
            for (int rt = 0; rt < 2; ++rt) {
                float xv[8];
                if (l == 0) {
                    float4 v0 = xa[rt][kc][0], v1 = xa[rt][kc][1];
                    xv[0]=v0.x; xv[1]=v0.y; xv[2]=v0.z; xv[3]=v0.w;
                    xv[4]=v1.x; xv[5]=v1.y; xv[6]=v1.z; xv[7]=v1.w;
                } else {
                    const float* sp = &scr[rg][rt][m16][kc * 32 + q * 8];
                    float4 v0 = *(const float4*)sp, v1 = *(const float4*)(sp + 4);
                    xv[0]=v0.x; xv[1]=v0.y; xv[2]=v0.z; xv[3]=v0.w;
                    xv[4]=v1.x; xv[5]=v1.y; xv[6]=v1.z; xv[7]=v1.w;
                }
                #pragma unroll
                for (int j = 0; j < 8; ++j) split2h(xv[j], ahi[rt].h[j], alo[rt].h[j]);
            }
            #pragma unroll
            for (int ct = 0; ct < 4; ++ct) {
                const ushort_t* bp = Wl + (cbase + ct * 16 + m16) * KP + kc * 32 + q * 8;
                f16x8 bhi = *(const f16x8*)bp;
                f16x8 blo = *(const f16x8*)(bp + HL);
                #pragma unroll
                for (int rt = 0; rt < 2; ++rt) {
                    acc[rt][ct] = __builtin_amdgcn_mfma_f32_16x16x32_f16(ahi[rt].v, bhi, acc[rt][ct], 0, 0, 0);
                    acc[rt][ct] = __builtin_amdgcn_mfma_f32_16x16x32_f16(ahi[rt].v, blo, acc[rt][ct], 0, 0, 0);
                    acc[rt][ct] = __builtin_amdgcn_mfma_f32_16x16x32_f16(alo[rt].v, bhi, acc[rt][ct], 0, 0, 0);
                }
            }
        }
        __syncthreads();   // colgroup partner done reading scr(l-1) before overwrite
        float bv[4];
        #pragma unroll
        for (int ct = 0; ct < 4; ++ct) bv[ct] = bs[l * D + cbase + ct * 16 + m16];
        #pragma unroll
        for (int rt = 0; rt < 2; ++rt)
            #pragma unroll
            for (int ct = 0; ct < 4; ++ct)
                #pragma unroll
                for (int reg = 0; reg < 4; ++reg)
                    scr[rg][rt][q * 4 + reg][cbase + ct * 16 + m16] =
                        fmaxf(acc[rt][ct][reg] + bv[ct], 0.f);
    }
    __syncthreads();
    // coalesced epilogue: 128 rows x 32 float4 = 4096 float4, 8 iters x 512 thr
    #pragma unroll
    for (int it = 0; it < 8; ++it) {
        int flat = it * 512 + tid;
        int row = flat >> 5, c4 = flat & 31;
        int grow = brow0 + row;
        float4 v = *(const float4*)&scr[row >> 5][(row >> 4) & 1][row & 15][c4 * 4];
        if (grow < NODES_TOTAL)
            *(float4*)&out[(size_t)grow * D + c4 * 4] = v;
    }
}

// ---------------- small GEMM (rows<5000) + fused scores + per-layer max --------
__global__ __launch_bounds__(256)
void gsmall_kernel(const float* __restrict__ hin, const ushort_t* __restrict__ Wlg,
                   const float* __restrict__ a_s, const float* __restrict__ a_d,
                   float* __restrict__ h2, float* __restrict__ sv, float* __restrict__ dv,
                   uint_t* __restrict__ gmaxu) {
    __shared__ ushort_t Wl[WT_L];
    int tid = threadIdx.x;
    {
        const uint4* gw = (const uint4*)Wlg;
        uint4* lw = (uint4*)Wl;
        #pragma unroll
        for (int r = 0; r < 17; ++r) lw[r * 256 + tid] = gw[r * 256 + tid];
    }
    int w = tid >> 6, lane = tid & 63, q = lane >> 4, m16 = lane & 15;
    int row0 = blockIdx.x * 128 + w * 32;
    f32x4 acc[2][8];
    #pragma unroll
    for (int rt = 0; rt < 2; ++rt)
        #pragma unroll
        for (int ct = 0; ct < 8; ++ct) acc[rt][ct] = (f32x4){0.f, 0.f, 0.f, 0.f};
    float4 xa[2][4][2];
    #pragma unroll
    for (int rt = 0; rt < 2; ++rt) {
        int r = row0 + rt * 16 + m16;
        if (r > NODES_REAL - 1) r = NODES_REAL - 1;
        #pragma unroll
        for (int kc = 0; kc < 4; ++kc) {
            const float* gp = hin + (size_t)r * D + kc * 32 + q * 8;
            xa[rt][kc][0] = *(const float4*)gp;
            xa[rt][kc][1] = *(const float4*)(gp + 4);
        }
    }
    __syncthreads();
    #pragma unroll
    for (int kc = 0; kc < 4; ++kc) {
        H8 ahi[2], alo[2];
        #pragma unroll
        for (int rt = 0; rt < 2; ++rt) {
            float4 v0 = xa[rt][kc][0], v1 = xa[rt][kc][1];
            float xv[8] = {v0.x, v0.y, v0.z, v0.w, v1.x, v1.y, v1.z, v1.w};
            #pragma unroll
            for (int j = 0; j < 8; ++j) split2h(xv[j], ahi[rt].h[j], alo[rt].h[j]);
        }
        #pragma unroll
        for (int ct = 0; ct < 8; ++ct) {
            const ushort_t* bp = Wl + (ct * 16 + m16) * KP + kc * 32 + q * 8;
            f16x8 bhi = *(const f16x8*)bp;
            f16x8 blo = *(const f16x8*)(bp + HL);
            #pragma unroll
            for (int rt = 0; rt < 2; ++rt) {
                acc[rt][ct] = __builtin_amdgcn_mfma_f32_16x16x32_f16(ahi[rt].v, bhi, acc[rt][ct], 0, 0, 0);
                acc[rt][ct] = __builtin_amdgcn_mfma_f32_16x16x32_f16(ahi[rt].v, blo, acc[rt][ct], 0, 0, 0);
                acc[rt][ct] = __builtin_amdgcn_mfma_f32_16x16x32_f16(alo[rt].v, bhi, acc[rt][ct], 0, 0, 0);
            }
        }
    }
    #pragma unroll
    for (int rt = 0; rt < 2; ++rt)
        #pragma unroll
        for (int reg = 0; reg < 4; ++reg) {
            int grow = row0 + rt * 16 + q * 4 + reg;
            if (grow < NODES_REAL) {
                #pragma unroll
                for (int ct = 0; ct < 8; ++ct)
                    h2[(size_t)grow * D + ct * 16 + m16] = acc[rt][ct][reg];
            }
        }
    float asv[8], adv[8];
    #pragma unroll
    for (int ct = 0; ct < 8; ++ct) { asv[ct] = a_s[ct * 16 + m16]; adv[ct] = a_d[ct * 16 + m16]; }
    #pragma unroll
    for (int rt = 0; rt < 2; ++rt)
        #pragma unroll
        for (int reg = 0; reg < 4; ++reg) {
            float ps = 0.f, pd = 0.f;
            #pragma unroll
            for (int ct = 0; ct < 8; ++ct) {
                float v = acc[rt][ct][reg];
                ps += v * asv[ct]; pd += v * adv[ct];
            }
            #pragma unroll
            for (int o = 1; o < 16; o <<= 1) { ps += __shfl_xor(ps, o); pd += __shfl_xor(pd, o); }
            int grow = row0 + rt * 16 + q * 4 + reg;
            if (m16 == 0 && grow < NODES_REAL) {
                sv[grow] = ps; dv[grow] = pd;
                atomicMax(gmaxu, encmax(ps));
            }
        }
}

// ---------------- aggregation: one wave per dst, global-bound softmax ----------
__global__ __launch_bounds__(256)
void agg_kernel(const float* __restrict__ h2, const float* __restrict__ sv,
                const float* __restrict__ dv, const int* __restrict__ offs,
                const ushort_t* __restrict__ esrc, const float* __restrict__ bias,
                float* __restrict__ out, const uint_t* __restrict__ gmaxu) {
    int w = threadIdx.x >> 6, lane = threadIdx.x & 63;
    int i = blockIdx.x * 4 + w;
    int start = offs[i], end = offs[i + 1];
    float d_i = dv[i];
    float gm = decmax(*gmaxu) + d_i;
    float m = gm > 0.f ? gm : NEG * gm;
    float ax = 0.f, ay = 0.f, exs = 0.f;
    for (int base = start; base < end; base += 64) {
        int cnt = min(64, end - base);
        int srci = (lane < cnt) ? (int)esrc[base + lane] : 0;
        float sc = sv[srci] + d_i;
        sc = sc > 0.f ? sc : NEG * sc;
        float ex = (lane < cnt) ? __expf(sc - m) : 0.f;
        exs += ex;
        if (cnt == 64) {
            #pragma unroll 4
            for (int j = 0; j < 64; ++j) {
                int   src = __shfl(srci, j);
                float e   = __shfl(ex, j);
                float2 hv = *(const float2*)&h2[(size_t)src * D + 2 * lane];
                ax += e * hv.x; ay += e * hv.y;
            }
        } else {
            for (int j = 0; j < cnt; ++j) {
                int   src = __shfl(srci, j);
                float e   = __shfl(ex, j);
                float2 hv = *(const float2*)&h2[(size_t)src * D + 2 * lane];
                ax += e * hv.x; ay += e * hv.y;
            }
        }
    }
    float scf = sv[i] + d_i; scf = scf > 0.f ? scf : NEG * scf;
    float exf = __expf(scf - m);
    float2 hv = *(const float2*)&h2[(size_t)i * D + 2 * lane];
    ax += exf * hv.x; ay += exf * hv.y;
    #pragma unroll
    for (int o = 1; o < 64; o <<= 1) exs += __shfl_xor(exs, o);
    float rd = 1.f / (exs + exf);
    float2 b2 = *(const float2*)&bias[2 * lane];
    float2 o2 = make_float2(fmaxf(ax * rd + b2.x, 0.f), fmaxf(ay * rd + b2.y, 0.f));
    *(float2*)&out[(size_t)i * D + 2 * lane] = o2;
}

// ---------------- launcher -----------------------------------------------------
extern "C" void kernel_launch(void* const* d_in, const int* in_sizes, int n_in,
                              void* d_out, int out_size, void* d_ws, size_t ws_size,
                              hipStream_t stream) {
    const float* x   = (const float*)d_in[0];
    const int*   ei  = (const int*)d_in[1];
    const float* Ws  = (const float*)d_in[2];
    const float* as_ = (const float*)d_in[3];
    const float* ad_ = (const float*)d_in[4];
    const float* bs  = (const float*)d_in[5];
    float* out = (float*)d_out;
    int Eh = in_sizes[1] / 2;                    // 1,280,000

    char* ws = (char*)d_ws;
    float*    h2     = (float*)ws;                        //  2,560,000
    float*    bufS   = (float*)(ws + 2560000);            //  2,560,000
    float*    sv     = (float*)(ws + 5120000);
    float*    dv     = (float*)(ws + 5140000);
    int*      counts = (int*)  (ws + 5160000);
    int*      offs   = (int*)  (ws + 5180000);
    ushort_t* rank16 = (ushort_t*)(ws + 5200016);         //  2,560,000
    ushort_t* esrc   = (ushort_t*)(ws + 7760016);         //  2,560,000
    ushort_t* Wt     = (ushort_t*)(ws + 10320016);        //    208,896
    uint_t*   gmaxu  = (uint_t*)(ws + 10528912);          //         12

    zero_kernel<<<(NODES_REAL + 255) / 256, 256, 0, stream>>>(counts, gmaxu);
    rank_kernel<<<(Eh + 255) / 256, 256, 0, stream>>>(ei, counts, rank16, Eh);
    scan_kernel<<<1, 1024, 0, stream>>>(counts, offs);
    scatter_det<<<(Eh + 255) / 256, 256, 0, stream>>>(ei, offs, rank16, esrc, Eh);
    wsplit_kernel<<<24, 256, 0, stream>>>(Ws, Wt);

    // rows >= 5000: fused 3-layer MLP, one HBM pass, 512-thr blocks (2 waves/SIMD)
    mlp3_kernel<<<(NODES_TOTAL - NODES_REAL + 127) / 128, 512, 0, stream>>>(x, Wt, bs, out);

    // rows < 5000: per-layer GAT pipeline
    for (int l = 0; l < 3; ++l) {
        const float* hin = (l == 0) ? x : bufS;
        float* hout = (l == 2) ? out : bufS;
        gsmall_kernel<<<(NODES_REAL + 127) / 128, 256, 0, stream>>>(
            hin, Wt + (size_t)l * WT_L, as_ + l * D, ad_ + l * D, h2, sv, dv, gmaxu + l);
        agg_kernel<<<(NODES_REAL + 3) / 4, 256, 0, stream>>>(
            h2, sv, dv, offs, esrc, bs + l * D, hout, gmaxu + l);
    }
}